// Round 1
// baseline (67.872 us; speedup 1.0000x reference)
//
#include <hip/hip_runtime.h>
#include <math.h>

#define NKHALF 16
#define NG 33          // 2*NKHALF+1
#define TPB 256

__device__ inline void inv3(const float* __restrict__ m, float* inv, float* detOut) {
    float c00 = m[4]*m[8] - m[5]*m[7];
    float c01 = m[5]*m[6] - m[3]*m[8];
    float c02 = m[3]*m[7] - m[4]*m[6];
    float det = m[0]*c00 + m[1]*c01 + m[2]*c02;
    float id  = 1.0f / det;
    inv[0] = c00 * id;
    inv[1] = (m[2]*m[7] - m[1]*m[8]) * id;
    inv[2] = (m[1]*m[5] - m[2]*m[4]) * id;
    inv[3] = c01 * id;
    inv[4] = (m[0]*m[8] - m[2]*m[6]) * id;
    inv[5] = (m[2]*m[3] - m[0]*m[5]) * id;
    inv[6] = c02 * id;
    inv[7] = (m[1]*m[6] - m[0]*m[7]) * id;
    inv[8] = (m[0]*m[4] - m[1]*m[3]) * id;
    *detOut = det;
}

// Kernel 1: per-atom complex exponential tables.
// ex[idx][a] = exp(i * (idx-16) * t0_a), t_i = 2*pi * sum_c Ainv[c][i] * pos_c
__global__ void build_tables(const float* __restrict__ pos,
                             const float* __restrict__ cell,
                             float2* __restrict__ ex,
                             float2* __restrict__ ey,
                             float2* __restrict__ ez,
                             int n) {
    int a = blockIdx.x * blockDim.x + threadIdx.x;
    if (a >= n) return;
    float inv[9], det;
    inv3(cell, inv, &det);
    const float twopi = 6.28318530717958647692f;
    float px = pos[3*a + 0], py = pos[3*a + 1], pz = pos[3*a + 2];
    float t0 = twopi * (inv[0]*px + inv[3]*py + inv[6]*pz);
    float t1 = twopi * (inv[1]*px + inv[4]*py + inv[7]*pz);
    float t2 = twopi * (inv[2]*px + inv[5]*py + inv[8]*pz);
    for (int idx = 0; idx < NG; ++idx) {
        float nv = (float)(idx - NKHALF);
        float s, c;
        sincosf(nv * t0, &s, &c);
        ex[idx * n + a] = make_float2(c, s);
        sincosf(nv * t1, &s, &c);
        ey[idx * n + a] = make_float2(c, s);
        sincosf(nv * t2, &s, &c);
        ez[idx * n + a] = make_float2(c, s);
    }
}

// Kernel 2: one block per (k1,k2); each thread accumulates S(k3) for all 33 k3.
__global__ __launch_bounds__(TPB) void structure_factor(
        const float2* __restrict__ ex, const float2* __restrict__ ey,
        const float2* __restrict__ ez,
        const float* __restrict__ q,
        const float* __restrict__ cell,
        const float* __restrict__ shift1, const float* __restrict__ amp1,
        int nshift,
        float* __restrict__ partials, int n) {
    const int bid = blockIdx.x;
    const int k1 = bid / NG;
    const int k2 = bid % NG;
    const int tid = threadIdx.x;

    float Sre[NG], Sim[NG];
#pragma unroll
    for (int i = 0; i < NG; ++i) { Sre[i] = 0.f; Sim[i] = 0.f; }

    const float2* exk = ex + (size_t)k1 * n;
    const float2* eyk = ey + (size_t)k2 * n;

    for (int a = tid; a < n; a += TPB) {
        float2 e1 = exk[a];
        float2 e2 = eyk[a];
        float qa  = q[a];
        float wr = qa * (e1.x*e2.x - e1.y*e2.y);
        float wi = qa * (e1.x*e2.y + e1.y*e2.x);
#pragma unroll
        for (int k3 = 0; k3 < NG; ++k3) {
            float2 e3 = ez[(size_t)k3 * n + a];
            Sre[k3] = fmaf(wr, e3.x, fmaf(-wi, e3.y, Sre[k3]));
            Sim[k3] = fmaf(wr, e3.y, fmaf( wi, e3.x, Sim[k3]));
        }
    }

    // wave-level butterfly reduce (64 lanes)
#pragma unroll
    for (int k3 = 0; k3 < NG; ++k3) {
        for (int off = 32; off; off >>= 1) {
            Sre[k3] += __shfl_down(Sre[k3], off, 64);
            Sim[k3] += __shfl_down(Sim[k3], off, 64);
        }
    }

    __shared__ float red[TPB/64][2*NG];
    const int wid = tid >> 6, lane = tid & 63;
    if (lane == 0) {
#pragma unroll
        for (int k3 = 0; k3 < NG; ++k3) {
            red[wid][2*k3 + 0] = Sre[k3];
            red[wid][2*k3 + 1] = Sim[k3];
        }
    }
    __syncthreads();
    if (tid < 2*NG) {
        float v = 0.f;
#pragma unroll
        for (int w = 0; w < TPB/64; ++w) v += red[w][tid];
        red[0][tid] = v;
    }
    __syncthreads();

    float cont = 0.f;
    if (tid < NG) {
        float sre = red[0][2*tid + 0];
        float sim = red[0][2*tid + 1];
        float inv[9], det;
        inv3(cell, inv, &det);
        const float twopi = 6.28318530717958647692f;
        float n1 = (float)(k1 - NKHALF);
        float n2 = (float)(k2 - NKHALF);
        float n3 = (float)(tid - NKHALF);
        // kvec_c = 2*pi * sum_i n_i * Ainv[c][i]
        float kx = twopi * (n1*inv[0] + n2*inv[1] + n3*inv[2]);
        float ky = twopi * (n1*inv[3] + n2*inv[4] + n3*inv[5]);
        float kz = twopi * (n1*inv[6] + n2*inv[7] + n3*inv[8]);
        float ksq = kx*kx + ky*ky + kz*kz;
        if (ksq > 0.f) {
            float kfac = 0.f;
            for (int j = 0; j < nshift; ++j) {
                float mt = -expf(2.0f * shift1[j]);
                kfac += amp1[j] * expf(ksq * mt);
            }
            cont = kfac * (sre*sre + sim*sim);
        }
    }
    if (tid < 64) {
        for (int off = 32; off; off >>= 1) cont += __shfl_down(cont, off, 64);
        if (tid == 0) partials[bid] = cont;
    }
}

// Kernel 3: sum partials, /volume, + ene_factor
__global__ void final_reduce(const float* __restrict__ partials, int np,
                             const float* __restrict__ cell,
                             const float* __restrict__ ene,
                             float* __restrict__ out) {
    const int tid = threadIdx.x;
    float v = 0.f;
    for (int i = tid; i < np; i += TPB) v += partials[i];
    for (int off = 32; off; off >>= 1) v += __shfl_down(v, off, 64);
    __shared__ float red[TPB/64];
    const int wid = tid >> 6, lane = tid & 63;
    if (lane == 0) red[wid] = v;
    __syncthreads();
    if (tid == 0) {
        float tot = 0.f;
        for (int w = 0; w < TPB/64; ++w) tot += red[w];
        float inv[9], det;
        inv3(cell, inv, &det);
        out[0] = tot / det + ene[0];
    }
}

extern "C" void kernel_launch(void* const* d_in, const int* in_sizes, int n_in,
                              void* d_out, int out_size, void* d_ws, size_t ws_size,
                              hipStream_t stream) {
    const float* pos    = (const float*)d_in[0];
    const float* q      = (const float*)d_in[1];
    const float* cell   = (const float*)d_in[2];
    const float* shift1 = (const float*)d_in[3];
    const float* amp1   = (const float*)d_in[4];
    const float* ene    = (const float*)d_in[5];
    // d_in[6] = batch (unused: single system)

    const int n      = in_sizes[0] / 3;
    const int nshift = in_sizes[3];

    float2* ex = (float2*)d_ws;
    float2* ey = ex + (size_t)NG * n;
    float2* ez = ey + (size_t)NG * n;
    float*  partials = (float*)(ez + (size_t)NG * n);

    build_tables<<<(n + 255)/256, 256, 0, stream>>>(pos, cell, ex, ey, ez, n);
    structure_factor<<<NG*NG, TPB, 0, stream>>>(ex, ey, ez, q, cell,
                                                shift1, amp1, nshift,
                                                partials, n);
    final_reduce<<<1, TPB, 0, stream>>>(partials, NG*NG, cell, ene, (float*)d_out);
}

// Round 2
// 61.605 us; speedup vs baseline: 1.1017x; 1.1017x over previous
//
#include <hip/hip_runtime.h>
#include <math.h>

#define NKHALF 16
#define NG 33              // 2*NKHALF+1
#define NPAIR (NG*NG)      // 1089 (k1,k2) pairs
#define NKVEC (NG*NG*NG)   // 35937 k-vectors
#define PAIRBLK 18         // ceil(NPAIR/64)

__device__ __forceinline__ void inv3(const float* __restrict__ m, float* inv, float* detOut) {
    float c00 = m[4]*m[8] - m[5]*m[7];
    float c01 = m[5]*m[6] - m[3]*m[8];
    float c02 = m[3]*m[7] - m[4]*m[6];
    float det = m[0]*c00 + m[1]*c01 + m[2]*c02;
    float id  = 1.0f / det;
    inv[0] = c00 * id;
    inv[1] = (m[2]*m[7] - m[1]*m[8]) * id;
    inv[2] = (m[1]*m[5] - m[2]*m[4]) * id;
    inv[3] = c01 * id;
    inv[4] = (m[0]*m[8] - m[2]*m[6]) * id;
    inv[5] = (m[2]*m[3] - m[0]*m[5]) * id;
    inv[6] = c02 * id;
    inv[7] = (m[1]*m[6] - m[0]*m[7]) * id;
    inv[8] = (m[0]*m[4] - m[1]*m[3]) * id;
    *detOut = det;
}

__device__ __forceinline__ float2 cmul(float2 a, float2 b) {
    return make_float2(a.x*b.x - a.y*b.y, a.x*b.y + a.y*b.x);
}

// Kernel 1: per-atom complex exponential tables, TRANSPOSED layout [atom][NG].
// exT[a*NG + idx] = exp(i * (idx-16) * t0_a). Built by recurrence from
// e1 = exp(i t); negative n via conjugate.
__global__ void build_tables(const float* __restrict__ pos,
                             const float* __restrict__ cell,
                             float2* __restrict__ exT,
                             float2* __restrict__ eyT,
                             float2* __restrict__ ezT,
                             int n) {
    int a = blockIdx.x * blockDim.x + threadIdx.x;
    if (a >= n) return;
    float inv[9], det;
    inv3(cell, inv, &det);
    const float twopi = 6.28318530717958647692f;
    float px = pos[3*a + 0], py = pos[3*a + 1], pz = pos[3*a + 2];
    float t[3];
    t[0] = twopi * (inv[0]*px + inv[3]*py + inv[6]*pz);
    t[1] = twopi * (inv[1]*px + inv[4]*py + inv[7]*pz);
    t[2] = twopi * (inv[2]*px + inv[5]*py + inv[8]*pz);
    float2* tabs[3];
    tabs[0] = exT + (size_t)a * NG;
    tabs[1] = eyT + (size_t)a * NG;
    tabs[2] = ezT + (size_t)a * NG;
    for (int ax = 0; ax < 3; ++ax) {
        float s, c;
        __sincosf(t[ax], &s, &c);
        float2 e1 = make_float2(c, s);
        float2 cur = make_float2(1.f, 0.f);
        float2* tb = tabs[ax];
        tb[NKHALF] = cur;
        for (int nn = 1; nn <= NKHALF; ++nn) {
            cur = cmul(cur, e1);
            tb[NKHALF + nn] = cur;
            tb[NKHALF - nn] = make_float2(cur.x, -cur.y);
        }
    }
}

// Kernel 2: thread = one (k1,k2) pair, 33 complex k3-accumulators in registers.
// Atom dimension split into chunks; partial S written per chunk.
// partials layout: [chunk][k3*NPAIR + pair] (coalesced both on write and read).
__global__ __launch_bounds__(64) void sf_chunked(
        const float2* __restrict__ exT, const float2* __restrict__ eyT,
        const float2* __restrict__ ezT,
        const float* __restrict__ q,
        float2* __restrict__ partials,
        int n, int chunkAtoms) {
    const int bid = blockIdx.x;
    const int pb = bid % PAIRBLK;     // consecutive bids share the atom chunk
    const int c  = bid / PAIRBLK;
    const int pair = pb * 64 + threadIdx.x;
    if (pair >= NPAIR) return;
    const int k1 = pair / NG;
    const int k2 = pair % NG;

    float2 S[NG];
#pragma unroll
    for (int i = 0; i < NG; ++i) S[i] = make_float2(0.f, 0.f);

    const int a0 = c * chunkAtoms;
    const int a1 = (a0 + chunkAtoms < n) ? a0 + chunkAtoms : n;

    for (int a = a0; a < a1; ++a) {
        float qa = q[a];
        float2 e1 = exT[(size_t)a * NG + k1];
        float2 e2 = eyT[(size_t)a * NG + k2];
        float wr = qa * (e1.x*e2.x - e1.y*e2.y);
        float wi = qa * (e1.x*e2.y + e1.y*e2.x);
        const float2* __restrict__ ez = ezT + (size_t)a * NG;
#pragma unroll
        for (int k3 = 0; k3 < NG; ++k3) {
            float2 e3 = ez[k3];
            S[k3].x = fmaf(wr, e3.x, fmaf(-wi, e3.y, S[k3].x));
            S[k3].y = fmaf(wi, e3.x, fmaf( wr, e3.y, S[k3].y));
        }
    }

    float2* __restrict__ out = partials + (size_t)c * NKVEC;
#pragma unroll
    for (int k3 = 0; k3 < NG; ++k3) {
        out[(size_t)k3 * NPAIR + pair] = S[k3];
    }
}

// Kernel 3: thread = one k-vector; sum chunk partials, apply weight*kfac*|S|^2,
// block-reduce to one partial per block.
__global__ __launch_bounds__(256) void reduce_weight(
        const float2* __restrict__ partials, int nChunks,
        const float* __restrict__ cell,
        const float* __restrict__ shift1, const float* __restrict__ amp1,
        int nshift,
        float* __restrict__ blockpart) {
    const int kv = blockIdx.x * 256 + threadIdx.x;
    float cont = 0.f;
    if (kv < NKVEC) {
        float sre = 0.f, sim = 0.f;
        for (int c = 0; c < nChunks; ++c) {
            float2 p = partials[(size_t)c * NKVEC + kv];
            sre += p.x;
            sim += p.y;
        }
        const int k3   = kv / NPAIR;
        const int pair = kv % NPAIR;
        const int k1 = pair / NG;
        const int k2 = pair % NG;
        float inv[9], det;
        inv3(cell, inv, &det);
        const float twopi = 6.28318530717958647692f;
        float n1 = (float)(k1 - NKHALF);
        float n2 = (float)(k2 - NKHALF);
        float n3 = (float)(k3 - NKHALF);
        float kx = twopi * (n1*inv[0] + n2*inv[1] + n3*inv[2]);
        float ky = twopi * (n1*inv[3] + n2*inv[4] + n3*inv[5]);
        float kz = twopi * (n1*inv[6] + n2*inv[7] + n3*inv[8]);
        float ksq = kx*kx + ky*ky + kz*kz;
        if (ksq > 0.f) {
            float kfac = 0.f;
            for (int j = 0; j < nshift; ++j) {
                float mt = -expf(2.0f * shift1[j]);
                kfac += amp1[j] * expf(ksq * mt);
            }
            cont = kfac * (sre*sre + sim*sim);
        }
    }
    // block reduction
    for (int off = 32; off; off >>= 1) cont += __shfl_down(cont, off, 64);
    __shared__ float red[4];
    const int wid = threadIdx.x >> 6, lane = threadIdx.x & 63;
    if (lane == 0) red[wid] = cont;
    __syncthreads();
    if (threadIdx.x == 0) {
        float v = red[0] + red[1] + red[2] + red[3];
        blockpart[blockIdx.x] = v;
    }
}

// Kernel 4: final sum, /volume, + ene_factor
__global__ void final_reduce(const float* __restrict__ blockpart, int np,
                             const float* __restrict__ cell,
                             const float* __restrict__ ene,
                             float* __restrict__ out) {
    const int tid = threadIdx.x;
    float v = 0.f;
    for (int i = tid; i < np; i += 256) v += blockpart[i];
    for (int off = 32; off; off >>= 1) v += __shfl_down(v, off, 64);
    __shared__ float red[4];
    const int wid = tid >> 6, lane = tid & 63;
    if (lane == 0) red[wid] = v;
    __syncthreads();
    if (tid == 0) {
        float tot = red[0] + red[1] + red[2] + red[3];
        float inv[9], det;
        inv3(cell, inv, &det);
        out[0] = tot / det + ene[0];
    }
}

extern "C" void kernel_launch(void* const* d_in, const int* in_sizes, int n_in,
                              void* d_out, int out_size, void* d_ws, size_t ws_size,
                              hipStream_t stream) {
    const float* pos    = (const float*)d_in[0];
    const float* q      = (const float*)d_in[1];
    const float* cell   = (const float*)d_in[2];
    const float* shift1 = (const float*)d_in[3];
    const float* amp1   = (const float*)d_in[4];
    const float* ene    = (const float*)d_in[5];
    // d_in[6] = batch (unused: single system)

    const int n      = in_sizes[0] / 3;
    const int nshift = in_sizes[3];

    const size_t tabElems = (size_t)n * NG;
    float2* exT = (float2*)d_ws;
    float2* eyT = exT + tabElems;
    float2* ezT = eyT + tabElems;
    float2* partials = ezT + tabElems;

    const int nb3 = (NKVEC + 255) / 256;   // 141 reduce blocks
    size_t used = (size_t)((char*)partials - (char*)d_ws);
    size_t reserve = used + (size_t)nb3 * sizeof(float) + 256;
    size_t avail = (ws_size > reserve) ? (ws_size - reserve) : 0;
    int AS = (int)(avail / ((size_t)NKVEC * sizeof(float2)));
    if (AS > 56) AS = 56;
    if (AS < 1)  AS = 1;
    int chunkAtoms = (n + AS - 1) / AS;
    int nChunks    = (n + chunkAtoms - 1) / chunkAtoms;

    float* blockpart = (float*)(partials + (size_t)nChunks * NKVEC);

    build_tables<<<(n + 255)/256, 256, 0, stream>>>(pos, cell, exT, eyT, ezT, n);
    sf_chunked<<<PAIRBLK * nChunks, 64, 0, stream>>>(exT, eyT, ezT, q,
                                                     partials, n, chunkAtoms);
    reduce_weight<<<nb3, 256, 0, stream>>>(partials, nChunks, cell,
                                           shift1, amp1, nshift, blockpart);
    final_reduce<<<1, 256, 0, stream>>>(blockpart, nb3, cell, ene, (float*)d_out);
}

// Round 3
// 48.658 us; speedup vs baseline: 1.3949x; 1.2661x over previous
//
#include <hip/hip_runtime.h>
#include <math.h>

#define NKHALF 16
#define NG 33                 // 2*NKHALF+1
#define NEX 17                // ex table entries: n1 in [0,16]
#define NPH 545               // hemisphere (k1,k2) pairs
#define NPHPAD 576            // padded to 9 groups of 64
#define NPG 9                 // pair groups
#define KVH (NG * NPHPAD)     // 19008 padded hemisphere k-slots
#define RW_BLOCKS (KVH / 64)  // 297, exact

__device__ __forceinline__ void inv3(const float* __restrict__ m, float* inv, float* detOut) {
    float c00 = m[4]*m[8] - m[5]*m[7];
    float c01 = m[5]*m[6] - m[3]*m[8];
    float c02 = m[3]*m[7] - m[4]*m[6];
    float det = m[0]*c00 + m[1]*c01 + m[2]*c02;
    float id  = 1.0f / det;
    inv[0] = c00 * id;
    inv[1] = (m[2]*m[7] - m[1]*m[8]) * id;
    inv[2] = (m[1]*m[5] - m[2]*m[4]) * id;
    inv[3] = c01 * id;
    inv[4] = (m[0]*m[8] - m[2]*m[6]) * id;
    inv[5] = (m[2]*m[3] - m[0]*m[5]) * id;
    inv[6] = c02 * id;
    inv[7] = (m[1]*m[6] - m[0]*m[7]) * id;
    inv[8] = (m[0]*m[4] - m[1]*m[3]) * id;
    *detOut = det;
}

__device__ __forceinline__ float2 cmul(float2 a, float2 b) {
    return make_float2(a.x*b.x - a.y*b.y, a.x*b.y + a.y*b.x);
}

// hp -> (n1, k2) for the hemisphere:
//   hp in [0,528):   n1 = hp/33 + 1, k2 = hp%33        (n1 in [1,16], n2 full)
//   hp in [528,544): n1 = 0,         k2 = hp-528+17    (n2 in [1,16])
//   hp == 544:       n1 = 0,         k2 = 16           (n2 = 0)
__device__ __forceinline__ void decode_pair(int hp, int* n1, int* k2) {
    if (hp < 528)      { int a = hp / 33; *n1 = a + 1; *k2 = hp - a * 33; }
    else if (hp < 544) { *n1 = 0; *k2 = hp - 528 + 17; }
    else               { *n1 = 0; *k2 = 16; }
}

// Kernel 1: per-atom tables. ex row (17 entries, n1 in [0,16]) has q folded in.
__global__ void build_tables(const float* __restrict__ pos,
                             const float* __restrict__ q,
                             const float* __restrict__ cell,
                             float2* __restrict__ exT,
                             float2* __restrict__ eyT,
                             float2* __restrict__ ezT,
                             int n) {
    int a = blockIdx.x * blockDim.x + threadIdx.x;
    if (a >= n) return;
    float inv[9], det;
    inv3(cell, inv, &det);
    const float twopi = 6.28318530717958647692f;
    float px = pos[3*a + 0], py = pos[3*a + 1], pz = pos[3*a + 2];
    float t0 = twopi * (inv[0]*px + inv[3]*py + inv[6]*pz);
    float t1 = twopi * (inv[1]*px + inv[4]*py + inv[7]*pz);
    float t2 = twopi * (inv[2]*px + inv[5]*py + inv[8]*pz);
    float qa = q[a];

    // ex: q-folded, n1 in [0,16]
    {
        float s, c;
        __sincosf(t0, &s, &c);
        float2 e1 = make_float2(c, s);
        float2 cur = make_float2(qa, 0.f);
        float2* tb = exT + (size_t)a * NEX;
        tb[0] = cur;
        for (int nn = 1; nn <= NKHALF; ++nn) {
            cur = cmul(cur, e1);
            tb[nn] = cur;
        }
    }
    // ey, ez: full 33 entries centered at idx 16
    {
        float s, c;
        __sincosf(t1, &s, &c);
        float2 e1 = make_float2(c, s);
        float2 cur = make_float2(1.f, 0.f);
        float2* tb = eyT + (size_t)a * NG;
        tb[NKHALF] = cur;
        for (int nn = 1; nn <= NKHALF; ++nn) {
            cur = cmul(cur, e1);
            tb[NKHALF + nn] = cur;
            tb[NKHALF - nn] = make_float2(cur.x, -cur.y);
        }
    }
    {
        float s, c;
        __sincosf(t2, &s, &c);
        float2 e1 = make_float2(c, s);
        float2 cur = make_float2(1.f, 0.f);
        float2* tb = ezT + (size_t)a * NG;
        tb[NKHALF] = cur;
        for (int nn = 1; nn <= NKHALF; ++nn) {
            cur = cmul(cur, e1);
            tb[NKHALF + nn] = cur;
            tb[NKHALF - nn] = make_float2(cur.x, -cur.y);
        }
    }
}

// Kernel 2: block = 192 threads = 3 waves; wave -> one pair-group (9 groups, 3 blocks).
// Lane = one hemisphere (k1,k2) pair, all 33 k3 accumulators in registers.
// ez row address is wave-uniform -> scalarizable; q folded into e1.
// partials layout: [chunk][k3*576 + slot] (coalesced write and read).
__global__ __launch_bounds__(192) void sf_hemi(
        const float2* __restrict__ exT, const float2* __restrict__ eyT,
        const float2* __restrict__ ezT,
        float2* __restrict__ partials,
        int n, int chunkAtoms) {
    const int c    = blockIdx.x / 3;
    const int pg   = (blockIdx.x % 3) * 3 + (threadIdx.x >> 6);
    const int lane = threadIdx.x & 63;
    const int slot = pg * 64 + lane;          // 0..575 (write slot)
    int hp = slot > 544 ? 544 : slot;         // clamp pads onto pair 544
    int n1, k2;
    decode_pair(hp, &n1, &k2);

    float2 S[NG];
#pragma unroll
    for (int i = 0; i < NG; ++i) S[i] = make_float2(0.f, 0.f);

    const int a0 = c * chunkAtoms;
    int a1 = a0 + chunkAtoms; if (a1 > n) a1 = n;

    for (int a = a0; a < a1; ++a) {
        float2 e1 = exT[(size_t)a * NEX + n1];   // q-folded
        float2 e2 = eyT[(size_t)a * NG + k2];
        float wr  = e1.x*e2.x - e1.y*e2.y;
        float wi  = e1.x*e2.y + e1.y*e2.x;
        float nwi = -wi;
        const float2* __restrict__ ez = ezT + (size_t)a * NG;  // uniform addr
#pragma unroll
        for (int k3 = 0; k3 < NG; ++k3) {
            float2 e3 = ez[k3];
            S[k3].x = fmaf(wr, e3.x, fmaf(nwi, e3.y, S[k3].x));
            S[k3].y = fmaf(wi, e3.x, fmaf(wr,  e3.y, S[k3].y));
        }
    }

    float2* __restrict__ out = partials + (size_t)c * KVH;
#pragma unroll
    for (int k3 = 0; k3 < NG; ++k3) {
        out[(size_t)k3 * NPHPAD + slot] = S[k3];
    }
}

// Kernel 3: block = 256 threads; 64 k-slots per block, 4 waves split the chunks,
// LDS-combine, wave 0 applies weight * kfac * |S|^2 and block-reduces.
__global__ __launch_bounds__(256) void reduce_weight(
        const float2* __restrict__ partials, int nChunks,
        const float* __restrict__ cell,
        const float* __restrict__ shift1, const float* __restrict__ amp1,
        int nshift,
        float* __restrict__ blockpart) {
    const int lane = threadIdx.x & 63;
    const int w    = threadIdx.x >> 6;
    const int kvs  = blockIdx.x * 64 + lane;   // [0, KVH), exact grid

    float sre = 0.f, sim = 0.f;
    for (int c = w; c < nChunks; c += 4) {
        float2 p = partials[(size_t)c * KVH + kvs];
        sre += p.x;
        sim += p.y;
    }
    __shared__ float2 red[4][64];
    red[w][lane] = make_float2(sre, sim);
    __syncthreads();

    if (w == 0) {
        sre = red[0][lane].x + red[1][lane].x + red[2][lane].x + red[3][lane].x;
        sim = red[0][lane].y + red[1][lane].y + red[2][lane].y + red[3][lane].y;

        const int k3 = kvs / NPHPAD;
        const int s  = kvs - k3 * NPHPAD;      // slot within pad
        float cont = 0.f;
        if (s < NPH) {
            int n1i, k2;
            decode_pair(s, &n1i, &k2);
            float n1 = (float)n1i;
            float n2 = (float)(k2 - NKHALF);
            float n3 = (float)(k3 - NKHALF);
            float factor = (s == 544) ? ((n3 != 0.f) ? 1.f : 0.f) : 2.f;

            float inv[9], det;
            inv3(cell, inv, &det);
            const float twopi = 6.28318530717958647692f;
            float kx = twopi * (n1*inv[0] + n2*inv[1] + n3*inv[2]);
            float ky = twopi * (n1*inv[3] + n2*inv[4] + n3*inv[5]);
            float kz = twopi * (n1*inv[6] + n2*inv[7] + n3*inv[8]);
            float ksq = kx*kx + ky*ky + kz*kz;
            float kfac = 0.f;
            for (int j = 0; j < nshift; ++j) {
                float mt = -expf(2.0f * shift1[j]);
                kfac += amp1[j] * expf(ksq * mt);
            }
            cont = factor * kfac * (sre*sre + sim*sim);
        }
        for (int off = 32; off; off >>= 1) cont += __shfl_down(cont, off, 64);
        if (lane == 0) blockpart[blockIdx.x] = cont;
    }
}

// Kernel 4: final sum, /volume, + ene_factor
__global__ void final_reduce(const float* __restrict__ blockpart, int np,
                             const float* __restrict__ cell,
                             const float* __restrict__ ene,
                             float* __restrict__ out) {
    const int tid = threadIdx.x;
    float v = 0.f;
    for (int i = tid; i < np; i += 256) v += blockpart[i];
    for (int off = 32; off; off >>= 1) v += __shfl_down(v, off, 64);
    __shared__ float red[4];
    const int wid = tid >> 6, lane = tid & 63;
    if (lane == 0) red[wid] = v;
    __syncthreads();
    if (tid == 0) {
        float tot = red[0] + red[1] + red[2] + red[3];
        float inv[9], det;
        inv3(cell, inv, &det);
        out[0] = tot / det + ene[0];
    }
}

extern "C" void kernel_launch(void* const* d_in, const int* in_sizes, int n_in,
                              void* d_out, int out_size, void* d_ws, size_t ws_size,
                              hipStream_t stream) {
    const float* pos    = (const float*)d_in[0];
    const float* q      = (const float*)d_in[1];
    const float* cell   = (const float*)d_in[2];
    const float* shift1 = (const float*)d_in[3];
    const float* amp1   = (const float*)d_in[4];
    const float* ene    = (const float*)d_in[5];
    // d_in[6] = batch (unused: single system)

    const int n      = in_sizes[0] / 3;
    const int nshift = in_sizes[3];

    // workspace layout
    float2* exT = (float2*)d_ws;
    float2* eyT = exT + (size_t)n * NEX;
    float2* ezT = eyT + (size_t)n * NG;
    float2* partials = ezT + (size_t)n * NG;
    size_t fixedBytes = (size_t)((char*)partials - (char*)d_ws);

    // pick chunkAtoms (>=12) so partials fit in the workspace
    int chunkAtoms = 12;
    int nChunks;
    for (;;) {
        nChunks = (n + chunkAtoms - 1) / chunkAtoms;
        size_t need = fixedBytes + (size_t)nChunks * KVH * sizeof(float2)
                      + (size_t)RW_BLOCKS * sizeof(float) + 1024;
        if (need <= ws_size || chunkAtoms >= n) break;
        chunkAtoms *= 2;
    }
    float* blockpart = (float*)(partials + (size_t)nChunks * KVH);

    build_tables<<<(n + 255)/256, 256, 0, stream>>>(pos, q, cell, exT, eyT, ezT, n);
    sf_hemi<<<3 * nChunks, 192, 0, stream>>>(exT, eyT, ezT, partials, n, chunkAtoms);
    reduce_weight<<<RW_BLOCKS, 256, 0, stream>>>(partials, nChunks, cell,
                                                 shift1, amp1, nshift, blockpart);
    final_reduce<<<1, 256, 0, stream>>>(blockpart, RW_BLOCKS, cell, ene, (float*)d_out);
}

// Round 4
// 43.123 us; speedup vs baseline: 1.5739x; 1.1284x over previous
//
#include <hip/hip_runtime.h>
#include <hip/hip_fp16.h>
#include <math.h>

#define NKHALF 16
#define NG 33                 // 2*NKHALF+1
#define NEX 17                // ex entries: n1 in [0,16], q folded in
#define NGP 34                // padded ez pitch in float2 (272B = 17 float4)
#define NPH 545               // hemisphere (k1,k2) pairs
#define NPHPAD 576            // padded to 9 groups of 64
#define KVH (NG * NPHPAD)     // 19008 padded hemisphere k-slots
#define RW_BLOCKS (KVH / 64)  // 297, exact

__device__ __forceinline__ void inv3(const float* __restrict__ m, float* inv, float* detOut) {
    float c00 = m[4]*m[8] - m[5]*m[7];
    float c01 = m[5]*m[6] - m[3]*m[8];
    float c02 = m[3]*m[7] - m[4]*m[6];
    float det = m[0]*c00 + m[1]*c01 + m[2]*c02;
    float id  = 1.0f / det;
    inv[0] = c00 * id;
    inv[1] = (m[2]*m[7] - m[1]*m[8]) * id;
    inv[2] = (m[1]*m[5] - m[2]*m[4]) * id;
    inv[3] = c01 * id;
    inv[4] = (m[0]*m[8] - m[2]*m[6]) * id;
    inv[5] = (m[2]*m[3] - m[0]*m[5]) * id;
    inv[6] = c02 * id;
    inv[7] = (m[1]*m[6] - m[0]*m[7]) * id;
    inv[8] = (m[0]*m[4] - m[1]*m[3]) * id;
    *detOut = det;
}

__device__ __forceinline__ float2 cmul(float2 a, float2 b) {
    return make_float2(a.x*b.x - a.y*b.y, a.x*b.y + a.y*b.x);
}

// hp -> (n1, k2):
//   hp in [0,528):   n1 = hp/33 + 1, k2 = hp%33
//   hp in [528,544): n1 = 0,         k2 = hp-528+17
//   hp == 544:       n1 = 0,         k2 = 16
__device__ __forceinline__ void decode_pair(int hp, int* n1, int* k2) {
    if (hp < 528)      { int a = hp / 33; *n1 = a + 1; *k2 = hp - a * 33; }
    else if (hp < 544) { *n1 = 0; *k2 = hp - 528 + 17; }
    else               { *n1 = 0; *k2 = 16; }
}

// Kernel 1: tables. Block = 192 (3 waves); wave = axis, lane = atom.
__global__ __launch_bounds__(192) void build_tables(
        const float* __restrict__ pos,
        const float* __restrict__ q,
        const float* __restrict__ cell,
        float2* __restrict__ exT,
        float2* __restrict__ eyT,
        float2* __restrict__ ezT,
        int n) {
    const int a    = blockIdx.x * 64 + (threadIdx.x & 63);
    const int axis = threadIdx.x >> 6;
    if (a >= n) return;
    float inv[9], det;
    inv3(cell, inv, &det);
    const float twopi = 6.28318530717958647692f;
    float px = pos[3*a + 0], py = pos[3*a + 1], pz = pos[3*a + 2];
    float t;
    if (axis == 0)      t = twopi * (inv[0]*px + inv[3]*py + inv[6]*pz);
    else if (axis == 1) t = twopi * (inv[1]*px + inv[4]*py + inv[7]*pz);
    else                t = twopi * (inv[2]*px + inv[5]*py + inv[8]*pz);

    float s, c;
    __sincosf(t, &s, &c);
    float2 e1 = make_float2(c, s);

    if (axis == 0) {
        float2 cur = make_float2(q[a], 0.f);   // q folded in
        float2* tb = exT + (size_t)a * NEX;
        tb[0] = cur;
        for (int nn = 1; nn <= NKHALF; ++nn) {
            cur = cmul(cur, e1);
            tb[nn] = cur;
        }
    } else {
        float2* tb = (axis == 1) ? (eyT + (size_t)a * NG)
                                 : (ezT + (size_t)a * NGP);
        float2 cur = make_float2(1.f, 0.f);
        tb[NKHALF] = cur;
        for (int nn = 1; nn <= NKHALF; ++nn) {
            cur = cmul(cur, e1);
            tb[NKHALF + nn] = cur;
            tb[NKHALF - nn] = make_float2(cur.x, -cur.y);
        }
    }
}

// Kernel 2: task = (chunk, pair-group); 4 wave-tasks per 256-thread block.
// Lane = hemisphere pair; 33 complex k3 accumulators in registers.
// ez row read as 17 aligned float4 (uniform address).
__global__ __launch_bounds__(256) void sf_hemi(
        const float2* __restrict__ exT, const float2* __restrict__ eyT,
        const float4* __restrict__ ez4T,
        __half2* __restrict__ partials,
        int n, int chunkAtoms, int nTasks) {
    const int task = blockIdx.x * 4 + (threadIdx.x >> 6);
    if (task >= nTasks) return;
    const int c    = task / 9;
    const int pg   = task - c * 9;
    const int lane = threadIdx.x & 63;
    const int slot = pg * 64 + lane;          // 0..575
    int hp = slot > 544 ? 544 : slot;
    int n1, k2;
    decode_pair(hp, &n1, &k2);

    float Sre[NG], Sim[NG];
#pragma unroll
    for (int i = 0; i < NG; ++i) { Sre[i] = 0.f; Sim[i] = 0.f; }

    const int a0 = c * chunkAtoms;
    int a1 = a0 + chunkAtoms; if (a1 > n) a1 = n;

    for (int a = a0; a < a1; ++a) {
        float2 e1 = exT[(size_t)a * NEX + n1];   // q-folded
        float2 e2 = eyT[(size_t)a * NG + k2];
        float wr  = e1.x*e2.x - e1.y*e2.y;
        float wi  = e1.x*e2.y + e1.y*e2.x;
        float nwi = -wi;
        const float4* __restrict__ ez = ez4T + (size_t)a * 17;  // uniform addr
#pragma unroll
        for (int j = 0; j < 16; ++j) {
            float4 e3 = ez[j];
            const int k3 = 2*j;
            Sre[k3]   = fmaf(wr, e3.x, fmaf(nwi, e3.y, Sre[k3]));
            Sim[k3]   = fmaf(wi, e3.x, fmaf(wr,  e3.y, Sim[k3]));
            Sre[k3+1] = fmaf(wr, e3.z, fmaf(nwi, e3.w, Sre[k3+1]));
            Sim[k3+1] = fmaf(wi, e3.z, fmaf(wr,  e3.w, Sim[k3+1]));
        }
        {
            float4 e3 = ez[16];
            Sre[32] = fmaf(wr, e3.x, fmaf(nwi, e3.y, Sre[32]));
            Sim[32] = fmaf(wi, e3.x, fmaf(wr,  e3.y, Sim[32]));
        }
    }

    __half2* __restrict__ out = partials + (size_t)c * KVH;
#pragma unroll
    for (int k3 = 0; k3 < NG; ++k3) {
        out[(size_t)k3 * NPHPAD + slot] = __floats2half2_rn(Sre[k3], Sim[k3]);
    }
}

// Kernel 3: block = 1024 threads (16 waves); 64 k-slots per block; waves split
// the chunk dimension; LDS combine; wave 0 weights and block-reduces.
__global__ __launch_bounds__(1024) void reduce_weight(
        const __half2* __restrict__ partials, int nChunks,
        const float* __restrict__ cell,
        const float* __restrict__ shift1, const float* __restrict__ amp1,
        int nshift,
        float* __restrict__ blockpart) {
    const int lane = threadIdx.x & 63;
    const int w    = threadIdx.x >> 6;         // 0..15
    const int kvs  = blockIdx.x * 64 + lane;   // [0, KVH)

    float sre = 0.f, sim = 0.f;
    for (int c = w; c < nChunks; c += 16) {
        float2 p = __half22float2(partials[(size_t)c * KVH + kvs]);
        sre += p.x;
        sim += p.y;
    }
    __shared__ float2 red[16][64];
    red[w][lane] = make_float2(sre, sim);
    __syncthreads();

    if (w == 0) {
        sre = 0.f; sim = 0.f;
#pragma unroll
        for (int j = 0; j < 16; ++j) {
            float2 p = red[j][lane];
            sre += p.x; sim += p.y;
        }
        const int k3 = kvs / NPHPAD;
        const int s  = kvs - k3 * NPHPAD;
        float cont = 0.f;
        if (s < NPH) {
            int n1i, k2;
            decode_pair(s, &n1i, &k2);
            float n1 = (float)n1i;
            float n2 = (float)(k2 - NKHALF);
            float n3 = (float)(k3 - NKHALF);
            float factor = (s == 544) ? ((n3 != 0.f) ? 1.f : 0.f) : 2.f;

            float inv[9], det;
            inv3(cell, inv, &det);
            const float twopi = 6.28318530717958647692f;
            float kx = twopi * (n1*inv[0] + n2*inv[1] + n3*inv[2]);
            float ky = twopi * (n1*inv[3] + n2*inv[4] + n3*inv[5]);
            float kz = twopi * (n1*inv[6] + n2*inv[7] + n3*inv[8]);
            float ksq = kx*kx + ky*ky + kz*kz;
            float kfac = 0.f;
            for (int j = 0; j < nshift; ++j) {
                float mt = -expf(2.0f * shift1[j]);
                kfac += amp1[j] * expf(ksq * mt);
            }
            cont = factor * kfac * (sre*sre + sim*sim);
        }
        for (int off = 32; off; off >>= 1) cont += __shfl_down(cont, off, 64);
        if (lane == 0) blockpart[blockIdx.x] = cont;
    }
}

// Kernel 4: final sum, /volume, + ene_factor
__global__ void final_reduce(const float* __restrict__ blockpart, int np,
                             const float* __restrict__ cell,
                             const float* __restrict__ ene,
                             float* __restrict__ out) {
    const int tid = threadIdx.x;
    float v = 0.f;
    for (int i = tid; i < np; i += 256) v += blockpart[i];
    for (int off = 32; off; off >>= 1) v += __shfl_down(v, off, 64);
    __shared__ float red[4];
    const int wid = tid >> 6, lane = tid & 63;
    if (lane == 0) red[wid] = v;
    __syncthreads();
    if (tid == 0) {
        float tot = red[0] + red[1] + red[2] + red[3];
        float inv[9], det;
        inv3(cell, inv, &det);
        out[0] = tot / det + ene[0];
    }
}

extern "C" void kernel_launch(void* const* d_in, const int* in_sizes, int n_in,
                              void* d_out, int out_size, void* d_ws, size_t ws_size,
                              hipStream_t stream) {
    const float* pos    = (const float*)d_in[0];
    const float* q      = (const float*)d_in[1];
    const float* cell   = (const float*)d_in[2];
    const float* shift1 = (const float*)d_in[3];
    const float* amp1   = (const float*)d_in[4];
    const float* ene    = (const float*)d_in[5];
    // d_in[6] = batch (unused: single system)

    const int n      = in_sizes[0] / 3;
    const int nshift = in_sizes[3];

    // workspace layout
    float2* exT = (float2*)d_ws;
    float2* eyT = exT + (size_t)n * NEX;
    float2* ezT = eyT + (size_t)n * NG;          // pitch NGP, 16B-aligned rows
    __half2* partials = (__half2*)(ezT + (size_t)n * NGP);
    size_t fixedBytes = (size_t)((char*)partials - (char*)d_ws);

    // chunk sizing: start at 8 atoms/chunk, grow if workspace is tight
    int chunkAtoms = 8;
    int nChunks;
    for (;;) {
        nChunks = (n + chunkAtoms - 1) / chunkAtoms;
        size_t need = fixedBytes + (size_t)nChunks * KVH * sizeof(__half2)
                      + (size_t)RW_BLOCKS * sizeof(float) + 1024;
        if (need <= ws_size || chunkAtoms >= n) break;
        chunkAtoms *= 2;
    }
    float* blockpart = (float*)(partials + (size_t)nChunks * KVH);

    const int nTasks = 9 * nChunks;

    build_tables<<<(n + 63)/64, 192, 0, stream>>>(pos, q, cell, exT, eyT, ezT, n);
    sf_hemi<<<(nTasks + 3)/4, 256, 0, stream>>>(exT, eyT, (const float4*)ezT,
                                                partials, n, chunkAtoms, nTasks);
    reduce_weight<<<RW_BLOCKS, 1024, 0, stream>>>(partials, nChunks, cell,
                                                  shift1, amp1, nshift, blockpart);
    final_reduce<<<1, 256, 0, stream>>>(blockpart, RW_BLOCKS, cell, ene, (float*)d_out);
}

// Round 5
// 41.409 us; speedup vs baseline: 1.6391x; 1.0414x over previous
//
#include <hip/hip_runtime.h>
#include <hip/hip_fp16.h>
#include <math.h>

#define NKHALF 16
#define NG 33                 // 2*NKHALF+1
#define NPH 545               // hemisphere (k1,k2) pairs
#define NPHPAD 576            // padded to 9 groups of 64
#define KVH (NG * NPHPAD)     // 19008 padded hemisphere k-slots
#define RW_BLOCKS (KVH / 64)  // 297, exact

__device__ __forceinline__ void inv3(const float* __restrict__ m, float* inv, float* detOut) {
    float c00 = m[4]*m[8] - m[5]*m[7];
    float c01 = m[5]*m[6] - m[3]*m[8];
    float c02 = m[3]*m[7] - m[4]*m[6];
    float det = m[0]*c00 + m[1]*c01 + m[2]*c02;
    float id  = 1.0f / det;
    inv[0] = c00 * id;
    inv[1] = (m[2]*m[7] - m[1]*m[8]) * id;
    inv[2] = (m[1]*m[5] - m[2]*m[4]) * id;
    inv[3] = c01 * id;
    inv[4] = (m[0]*m[8] - m[2]*m[6]) * id;
    inv[5] = (m[2]*m[3] - m[0]*m[5]) * id;
    inv[6] = c02 * id;
    inv[7] = (m[1]*m[6] - m[0]*m[7]) * id;
    inv[8] = (m[0]*m[4] - m[1]*m[3]) * id;
    *detOut = det;
}

// hp -> (n1, k2):
//   hp in [0,528):   n1 = hp/33 + 1, k2 = hp%33
//   hp in [528,544): n1 = 0,         k2 = hp-528+17
//   hp == 544:       n1 = 0,         k2 = 16
__device__ __forceinline__ void decode_pair(int hp, int* n1, int* k2) {
    if (hp < 528)      { int a = hp / 33; *n1 = a + 1; *k2 = hp - a * 33; }
    else if (hp < 544) { *n1 = 0; *k2 = hp - 528 + 17; }
    else               { *n1 = 0; *k2 = 16; }
}

// Kernel A: fused tables + structure factor.
// Task = (atom-chunk, pair-group); 4 wave-tasks per 256-thread block.
// Lane = hemisphere pair; per atom: one sincos for the (n1,n2,-16) phase,
// then 33 k3 values via in-register complex rotation by e3 = exp(i*v2).
// Also zeroes d_out[0] (kernel B atomically accumulates into it).
__global__ __launch_bounds__(256, 4) void sf_fused(
        const float* __restrict__ pos,
        const float* __restrict__ q,
        const float* __restrict__ cell,
        __half2* __restrict__ partials,
        float* __restrict__ out0,
        int n, int chunkAtoms, int nTasks) {
    if (blockIdx.x == 0 && threadIdx.x == 0) out0[0] = 0.f;

    const int task = blockIdx.x * 4 + (threadIdx.x >> 6);
    if (task >= nTasks) return;
    const int c    = task / 9;
    const int pg   = task - c * 9;
    const int lane = threadIdx.x & 63;
    const int slot = pg * 64 + lane;          // 0..575
    int hp = slot > 544 ? 544 : slot;
    int n1i, k2;
    decode_pair(hp, &n1i, &k2);
    const float n1f = (float)n1i;
    const float n2f = (float)(k2 - NKHALF);

    float inv[9], det;
    inv3(cell, inv, &det);
    const float twopi = 6.28318530717958647692f;

    float Sre[NG], Sim[NG];
#pragma unroll
    for (int i = 0; i < NG; ++i) { Sre[i] = 0.f; Sim[i] = 0.f; }

    const int a0 = c * chunkAtoms;
    int a1 = a0 + chunkAtoms; if (a1 > n) a1 = n;

    for (int a = a0; a < a1; ++a) {
        // uniform-per-wave loads (scalarizable)
        float px = pos[3*a + 0], py = pos[3*a + 1], pz = pos[3*a + 2];
        float qa = q[a];
        float v0 = twopi * (inv[0]*px + inv[3]*py + inv[6]*pz);
        float v1 = twopi * (inv[1]*px + inv[4]*py + inv[7]*pz);
        float v2 = twopi * (inv[2]*px + inv[5]*py + inv[8]*pz);

        // phase at k3 index 0 (n3 = -16)
        float ph = fmaf(n1f, v0, fmaf(n2f, v1, -16.f * v2));
        float s, cc;
        __sincosf(ph, &s, &cc);
        float curx = qa * cc, cury = qa * s;

        float s3, c3;
        __sincosf(v2, &s3, &c3);     // rotation e3 = exp(i*v2), uniform per atom

#pragma unroll
        for (int k3 = 0; k3 < NG; ++k3) {
            Sre[k3] += curx;
            Sim[k3] += cury;
            if (k3 < NG - 1) {
                float nx = curx * c3 - cury * s3;
                float ny = fmaf(curx, s3, cury * c3);
                curx = nx; cury = ny;
            }
        }
    }

    __half2* __restrict__ out = partials + (size_t)c * KVH;
#pragma unroll
    for (int k3 = 0; k3 < NG; ++k3) {
        out[(size_t)k3 * NPHPAD + slot] = __floats2half2_rn(Sre[k3], Sim[k3]);
    }
}

// Kernel B: block = 1024 threads (16 waves) per 64 k-slots; waves split the
// chunk dim, LDS combine, wave 0 weights (incl. 1/volume) and one atomicAdd
// per block into d_out[0]; block 0 also adds ene_factor.
__global__ __launch_bounds__(1024) void reduce_weight(
        const __half2* __restrict__ partials, int nChunks,
        const float* __restrict__ cell,
        const float* __restrict__ shift1, const float* __restrict__ amp1,
        int nshift,
        const float* __restrict__ ene,
        float* __restrict__ out) {
    const int lane = threadIdx.x & 63;
    const int w    = threadIdx.x >> 6;         // 0..15
    const int kvs  = blockIdx.x * 64 + lane;   // [0, KVH)

    float sre = 0.f, sim = 0.f;
    for (int c = w; c < nChunks; c += 16) {
        float2 p = __half22float2(partials[(size_t)c * KVH + kvs]);
        sre += p.x;
        sim += p.y;
    }
    __shared__ float2 red[16][64];
    red[w][lane] = make_float2(sre, sim);
    __syncthreads();

    if (w == 0) {
        sre = 0.f; sim = 0.f;
#pragma unroll
        for (int j = 0; j < 16; ++j) {
            float2 p = red[j][lane];
            sre += p.x; sim += p.y;
        }
        const int k3 = kvs / NPHPAD;
        const int s  = kvs - k3 * NPHPAD;
        float cont = 0.f;
        float inv[9], det;
        inv3(cell, inv, &det);
        if (s < NPH) {
            int n1i, k2;
            decode_pair(s, &n1i, &k2);
            float n1 = (float)n1i;
            float n2 = (float)(k2 - NKHALF);
            float n3 = (float)(k3 - NKHALF);
            float factor = (s == 544) ? ((n3 != 0.f) ? 1.f : 0.f) : 2.f;

            const float twopi = 6.28318530717958647692f;
            float kx = twopi * (n1*inv[0] + n2*inv[1] + n3*inv[2]);
            float ky = twopi * (n1*inv[3] + n2*inv[4] + n3*inv[5]);
            float kz = twopi * (n1*inv[6] + n2*inv[7] + n3*inv[8]);
            float ksq = kx*kx + ky*ky + kz*kz;
            float kfac = 0.f;
            for (int j = 0; j < nshift; ++j) {
                float mt = -expf(2.0f * shift1[j]);
                kfac += amp1[j] * expf(ksq * mt);
            }
            cont = factor * kfac * (sre*sre + sim*sim) / det;
        }
        for (int off = 32; off; off >>= 1) cont += __shfl_down(cont, off, 64);
        if (lane == 0) {
            float add = cont;
            if (blockIdx.x == 0) add += ene[0];
            atomicAdd(out, add);
        }
    }
}

extern "C" void kernel_launch(void* const* d_in, const int* in_sizes, int n_in,
                              void* d_out, int out_size, void* d_ws, size_t ws_size,
                              hipStream_t stream) {
    const float* pos    = (const float*)d_in[0];
    const float* q      = (const float*)d_in[1];
    const float* cell   = (const float*)d_in[2];
    const float* shift1 = (const float*)d_in[3];
    const float* amp1   = (const float*)d_in[4];
    const float* ene    = (const float*)d_in[5];
    // d_in[6] = batch (unused: single system)

    const int n      = in_sizes[0] / 3;
    const int nshift = in_sizes[3];

    // workspace: only fp16 partials now
    __half2* partials = (__half2*)d_ws;

    // chunk sizing: start at 4 atoms/chunk (occupancy), grow if ws is tight
    int chunkAtoms = 4;
    int nChunks;
    for (;;) {
        nChunks = (n + chunkAtoms - 1) / chunkAtoms;
        size_t need = (size_t)nChunks * KVH * sizeof(__half2) + 1024;
        if (need <= ws_size || chunkAtoms >= n) break;
        chunkAtoms *= 2;
    }

    const int nTasks = 9 * nChunks;

    sf_fused<<<(nTasks + 3)/4, 256, 0, stream>>>(pos, q, cell, partials,
                                                 (float*)d_out,
                                                 n, chunkAtoms, nTasks);
    reduce_weight<<<RW_BLOCKS, 1024, 0, stream>>>(partials, nChunks, cell,
                                                  shift1, amp1, nshift,
                                                  ene, (float*)d_out);
}

// Round 6
// 28.399 us; speedup vs baseline: 2.3900x; 1.4581x over previous
//
#include <hip/hip_runtime.h>
#include <hip/hip_fp16.h>
#include <math.h>

#define NKHALF 16
#define NG 33                 // 2*NKHALF+1
#define NPH 545               // hemisphere (k1,k2) pairs
#define NPHPAD 576            // padded to 9 groups of 64
#define KVH (NG * NPHPAD)     // 19008 padded hemisphere k-slots
#define RW_BLOCKS (KVH / 64)  // 297, exact
#define CHUNK 8               // atoms per wave-task (compile-time)

__device__ __forceinline__ void inv3(const float* __restrict__ m, float* inv, float* detOut) {
    float c00 = m[4]*m[8] - m[5]*m[7];
    float c01 = m[5]*m[6] - m[3]*m[8];
    float c02 = m[3]*m[7] - m[4]*m[6];
    float det = m[0]*c00 + m[1]*c01 + m[2]*c02;
    float id  = 1.0f / det;
    inv[0] = c00 * id;
    inv[1] = (m[2]*m[7] - m[1]*m[8]) * id;
    inv[2] = (m[1]*m[5] - m[2]*m[4]) * id;
    inv[3] = c01 * id;
    inv[4] = (m[0]*m[8] - m[2]*m[6]) * id;
    inv[5] = (m[2]*m[3] - m[0]*m[5]) * id;
    inv[6] = c02 * id;
    inv[7] = (m[1]*m[6] - m[0]*m[7]) * id;
    inv[8] = (m[0]*m[4] - m[1]*m[3]) * id;
    *detOut = det;
}

// hp -> (n1, k2):
//   hp in [0,528):   n1 = hp/33 + 1, k2 = hp%33
//   hp in [528,544): n1 = 0,         k2 = hp-528+17
//   hp == 544:       n1 = 0,         k2 = 16
__device__ __forceinline__ void decode_pair(int hp, int* n1, int* k2) {
    if (hp < 528)      { int a = hp / 33; *n1 = a + 1; *k2 = hp - a * 33; }
    else if (hp < 544) { *n1 = 0; *k2 = hp - 528 + 17; }
    else               { *n1 = 0; *k2 = 16; }
}

// Kernel A: fused tables + structure factor + intra-block chunk combine.
// Block = 256 threads = 4 waves, ALL on the same pair-group pg; wave w works
// atom chunk quad*4+w (CHUNK=8 atoms). After compute, the 4 waves' S are
// combined through LDS and written as ONE partial per block -> partials
// shrink 4x (fully L2-resident). Also zeroes d_out[0] for kernel B's atomics.
__global__ __launch_bounds__(256) void sf_fused(
        const float* __restrict__ pos,
        const float* __restrict__ q,
        const float* __restrict__ cell,
        __half2* __restrict__ partials,
        float* __restrict__ out0,
        int n) {
    if (blockIdx.x == 0 && threadIdx.x == 0) out0[0] = 0.f;

    const int pg   = blockIdx.x % 9;
    const int quad = blockIdx.x / 9;
    const int w    = threadIdx.x >> 6;
    const int lane = threadIdx.x & 63;
    const int slot = pg * 64 + lane;          // 0..575
    int hp = slot > 544 ? 544 : slot;
    int n1i, k2;
    decode_pair(hp, &n1i, &k2);
    const float n1f = (float)n1i;
    const float n2f = (float)(k2 - NKHALF);

    float inv[9], det;
    inv3(cell, inv, &det);
    const float twopi = 6.28318530717958647692f;

    float Sre[NG], Sim[NG];
#pragma unroll
    for (int i = 0; i < NG; ++i) { Sre[i] = 0.f; Sim[i] = 0.f; }

    const int c  = quad * 4 + w;
    const int a0 = c * CHUNK;
    int a1 = a0 + CHUNK; if (a1 > n) a1 = n;

#pragma unroll 2
    for (int a = a0; a < a1; ++a) {
        float px = pos[3*a + 0], py = pos[3*a + 1], pz = pos[3*a + 2];
        float qa = q[a];
        float v0 = twopi * (inv[0]*px + inv[3]*py + inv[6]*pz);
        float v1 = twopi * (inv[1]*px + inv[4]*py + inv[7]*pz);
        float v2 = twopi * (inv[2]*px + inv[5]*py + inv[8]*pz);

        // phase at k3 index 0 (n3 = -16)
        float ph = fmaf(n1f, v0, fmaf(n2f, v1, -16.f * v2));
        float s, cc;
        __sincosf(ph, &s, &cc);
        float curx = qa * cc, cury = qa * s;

        float s3, c3;
        __sincosf(v2, &s3, &c3);     // rotation e3 = exp(i*v2)

#pragma unroll
        for (int k3 = 0; k3 < NG; ++k3) {
            Sre[k3] += curx;
            Sim[k3] += cury;
            if (k3 < NG - 1) {
                float nx = curx * c3 - cury * s3;
                float ny = fmaf(curx, s3, cury * c3);
                curx = nx; cury = ny;
            }
        }
    }

    // cross-wave combine: each wave dumps S (half2) to LDS, then all 256
    // threads cooperatively sum the 4 waves and write the block partial.
    __shared__ __half2 ls[4][NG][64];
#pragma unroll
    for (int k3 = 0; k3 < NG; ++k3) {
        ls[w][k3][lane] = __floats2half2_rn(Sre[k3], Sim[k3]);
    }
    __syncthreads();

    __half2* __restrict__ out = partials + (size_t)quad * KVH;
    for (int idx = threadIdx.x; idx < NG * 64; idx += 256) {
        const int k3 = idx >> 6;
        const int l  = idx & 63;
        float2 acc = __half22float2(ls[0][k3][l]);
        float2 p1  = __half22float2(ls[1][k3][l]);
        float2 p2  = __half22float2(ls[2][k3][l]);
        float2 p3  = __half22float2(ls[3][k3][l]);
        acc.x += p1.x + p2.x + p3.x;
        acc.y += p1.y + p2.y + p3.y;
        out[(size_t)k3 * NPHPAD + pg * 64 + l] = __floats2half2_rn(acc.x, acc.y);
    }
}

// Kernel B: block = 1024 threads (16 waves) per 64 k-slots; waves split the
// (small) chunk dim, LDS combine, wave 0 weights (incl. 1/volume) and one
// atomicAdd per block into d_out[0]; block 0 also adds ene_factor.
__global__ __launch_bounds__(1024) void reduce_weight(
        const __half2* __restrict__ partials, int nChunks,
        const float* __restrict__ cell,
        const float* __restrict__ shift1, const float* __restrict__ amp1,
        int nshift,
        const float* __restrict__ ene,
        float* __restrict__ out) {
    const int lane = threadIdx.x & 63;
    const int w    = threadIdx.x >> 6;         // 0..15
    const int kvs  = blockIdx.x * 64 + lane;   // [0, KVH)

    float sre = 0.f, sim = 0.f;
    for (int c = w; c < nChunks; c += 16) {
        float2 p = __half22float2(partials[(size_t)c * KVH + kvs]);
        sre += p.x;
        sim += p.y;
    }
    __shared__ float2 red[16][64];
    red[w][lane] = make_float2(sre, sim);
    __syncthreads();

    if (w == 0) {
        sre = 0.f; sim = 0.f;
#pragma unroll
        for (int j = 0; j < 16; ++j) {
            float2 p = red[j][lane];
            sre += p.x; sim += p.y;
        }
        const int k3 = kvs / NPHPAD;
        const int s  = kvs - k3 * NPHPAD;
        float cont = 0.f;
        float inv[9], det;
        inv3(cell, inv, &det);
        if (s < NPH) {
            int n1i, k2;
            decode_pair(s, &n1i, &k2);
            float n1 = (float)n1i;
            float n2 = (float)(k2 - NKHALF);
            float n3 = (float)(k3 - NKHALF);
            float factor = (s == 544) ? ((n3 != 0.f) ? 1.f : 0.f) : 2.f;

            const float twopi = 6.28318530717958647692f;
            float kx = twopi * (n1*inv[0] + n2*inv[1] + n3*inv[2]);
            float ky = twopi * (n1*inv[3] + n2*inv[4] + n3*inv[5]);
            float kz = twopi * (n1*inv[6] + n2*inv[7] + n3*inv[8]);
            float ksq = kx*kx + ky*ky + kz*kz;
            float kfac = 0.f;
            for (int j = 0; j < nshift; ++j) {
                float mt = -expf(2.0f * shift1[j]);
                kfac += amp1[j] * expf(ksq * mt);
            }
            cont = factor * kfac * (sre*sre + sim*sim) / det;
        }
        for (int off = 32; off; off >>= 1) cont += __shfl_down(cont, off, 64);
        if (lane == 0) {
            float add = cont;
            if (blockIdx.x == 0) add += ene[0];
            atomicAdd(out, add);
        }
    }
}

extern "C" void kernel_launch(void* const* d_in, const int* in_sizes, int n_in,
                              void* d_out, int out_size, void* d_ws, size_t ws_size,
                              hipStream_t stream) {
    const float* pos    = (const float*)d_in[0];
    const float* q      = (const float*)d_in[1];
    const float* cell   = (const float*)d_in[2];
    const float* shift1 = (const float*)d_in[3];
    const float* amp1   = (const float*)d_in[4];
    const float* ene    = (const float*)d_in[5];
    // d_in[6] = batch (unused: single system)

    const int n      = in_sizes[0] / 3;
    const int nshift = in_sizes[3];

    __half2* partials = (__half2*)d_ws;

    const int nChunks = (n + CHUNK - 1) / CHUNK;        // 250 for n=2000
    const int nQuads  = (nChunks + 3) / 4;              // 63

    sf_fused<<<9 * nQuads, 256, 0, stream>>>(pos, q, cell, partials,
                                             (float*)d_out, n);
    reduce_weight<<<RW_BLOCKS, 1024, 0, stream>>>(partials, nQuads, cell,
                                                  shift1, amp1, nshift,
                                                  ene, (float*)d_out);
}

// Round 7
// 27.232 us; speedup vs baseline: 2.4923x; 1.0428x over previous
//
#include <hip/hip_runtime.h>
#include <hip/hip_fp16.h>
#include <math.h>

#define NKHALF 16
#define NG 33                 // 2*NKHALF+1
#define NPH 545               // hemisphere (k1,k2) pairs
#define NPHPAD 576            // padded to 9 groups of 64
#define KVH (NG * NPHPAD)     // 19008 padded hemisphere k-slots
#define RW_BLOCKS (KVH / 64)  // 297, exact
#define CHUNK 8               // atoms per wave
#define WAVES_A 8             // waves per A block (same pair-group)

__device__ __forceinline__ void inv3(const float* __restrict__ m, float* inv, float* detOut) {
    float c00 = m[4]*m[8] - m[5]*m[7];
    float c01 = m[5]*m[6] - m[3]*m[8];
    float c02 = m[3]*m[7] - m[4]*m[6];
    float det = m[0]*c00 + m[1]*c01 + m[2]*c02;
    float id  = 1.0f / det;
    inv[0] = c00 * id;
    inv[1] = (m[2]*m[7] - m[1]*m[8]) * id;
    inv[2] = (m[1]*m[5] - m[2]*m[4]) * id;
    inv[3] = c01 * id;
    inv[4] = (m[0]*m[8] - m[2]*m[6]) * id;
    inv[5] = (m[2]*m[3] - m[0]*m[5]) * id;
    inv[6] = c02 * id;
    inv[7] = (m[1]*m[6] - m[0]*m[7]) * id;
    inv[8] = (m[0]*m[4] - m[1]*m[3]) * id;
    *detOut = det;
}

// hp -> (n1, k2):
//   hp in [0,528):   n1 = hp/33 + 1, k2 = hp%33
//   hp in [528,544): n1 = 0,         k2 = hp-528+17
//   hp == 544:       n1 = 0,         k2 = 16
__device__ __forceinline__ void decode_pair(int hp, int* n1, int* k2) {
    if (hp < 528)      { int a = hp / 33; *n1 = a + 1; *k2 = hp - a * 33; }
    else if (hp < 544) { *n1 = 0; *k2 = hp - 528 + 17; }
    else               { *n1 = 0; *k2 = 16; }
}

// Kernel A: block = 512 thr = 8 waves, all on pair-group pg; wave w handles
// atom chunk oct*8+w (8 atoms). Per atom: lanes 0..7 precompute
// (v0,v1,v2,qa,c3,s3) for the wave's 8 atoms; broadcast via shfl; each lane
// does ONE sincos (its pair phase) then walks 33 k3 by packed complex
// rotation. 8 waves LDS-combine -> one fp16 partial per block.
__global__ __launch_bounds__(512) void sf_fused(
        const float* __restrict__ pos,
        const float* __restrict__ q,
        const float* __restrict__ cell,
        __half2* __restrict__ partials,
        float* __restrict__ out0,
        int n) {
    if (blockIdx.x == 0 && threadIdx.x == 0) out0[0] = 0.f;

    const int pg   = blockIdx.x % 9;
    const int oct  = blockIdx.x / 9;
    const int w    = threadIdx.x >> 6;
    const int lane = threadIdx.x & 63;
    const int slot = pg * 64 + lane;          // 0..575
    int hp = slot > 544 ? 544 : slot;
    int n1i, k2;
    decode_pair(hp, &n1i, &k2);
    const float n1f = (float)n1i;
    const float n2f = (float)(k2 - NKHALF);

    float inv[9], det;
    inv3(cell, inv, &det);
    const float twopi = 6.28318530717958647692f;

    float2 S[NG];
#pragma unroll
    for (int i = 0; i < NG; ++i) S[i] = make_float2(0.f, 0.f);

    const int a0 = (oct * WAVES_A + w) * CHUNK;
    int na = n - a0; if (na > CHUNK) na = CHUNK;

    // lanes 0..na-1 precompute per-atom wave-uniform values
    float v0l = 0.f, v1l = 0.f, v2l = 0.f, qal = 0.f, c3l = 1.f, s3l = 0.f;
    if (lane < na) {
        int a = a0 + lane;
        float px = pos[3*a + 0], py = pos[3*a + 1], pz = pos[3*a + 2];
        qal = q[a];
        v0l = twopi * (inv[0]*px + inv[3]*py + inv[6]*pz);
        v1l = twopi * (inv[1]*px + inv[4]*py + inv[7]*pz);
        v2l = twopi * (inv[2]*px + inv[5]*py + inv[8]*pz);
        __sincosf(v2l, &s3l, &c3l);
    }

    for (int i = 0; i < na; ++i) {
        float v0 = __shfl(v0l, i, 64);
        float v1 = __shfl(v1l, i, 64);
        float v2 = __shfl(v2l, i, 64);
        float qa = __shfl(qal, i, 64);
        float c3 = __shfl(c3l, i, 64);
        float s3 = __shfl(s3l, i, 64);

        // phase at k3 index 0 (n3 = -16)
        float ph = fmaf(n1f, v0, fmaf(n2f, v1, -16.f * v2));
        float s, cc;
        __sincosf(ph, &s, &cc);
        float2 cur = make_float2(qa * cc, qa * s);

#pragma unroll
        for (int k3 = 0; k3 < NG; ++k3) {
            S[k3].x += cur.x;
            S[k3].y += cur.y;
            if (k3 < NG - 1) {
                float2 t;
                t.x = fmaf(-cur.y, s3, cur.x * c3);
                t.y = fmaf( cur.x, s3, cur.y * c3);
                cur = t;
            }
        }
    }

    // cross-wave combine through LDS (fp16), one partial per block
    __shared__ __half2 ls[WAVES_A][NG][64];
#pragma unroll
    for (int k3 = 0; k3 < NG; ++k3) {
        ls[w][k3][lane] = __floats2half2_rn(S[k3].x, S[k3].y);
    }
    __syncthreads();

    __half2* __restrict__ out = partials + (size_t)oct * KVH;
    for (int idx = threadIdx.x; idx < NG * 64; idx += 512) {
        const int k3 = idx >> 6;
        const int l  = idx & 63;
        float sx = 0.f, sy = 0.f;
#pragma unroll
        for (int j = 0; j < WAVES_A; ++j) {
            float2 p = __half22float2(ls[j][k3][l]);
            sx += p.x; sy += p.y;
        }
        out[(size_t)k3 * NPHPAD + pg * 64 + l] = __floats2half2_rn(sx, sy);
    }
}

// Kernel B: block = 512 thr (8 waves) per 64 k-slots; waves split the quad
// dim (4 loads each), LDS combine, wave 0 weights (incl. 1/volume) and one
// atomicAdd per block; block 0 adds ene_factor.
__global__ __launch_bounds__(512) void reduce_weight(
        const __half2* __restrict__ partials, int nQuads,
        const float* __restrict__ cell,
        const float* __restrict__ shift1, const float* __restrict__ amp1,
        int nshift,
        const float* __restrict__ ene,
        float* __restrict__ out) {
    const int lane = threadIdx.x & 63;
    const int w    = threadIdx.x >> 6;         // 0..7
    const int kvs  = blockIdx.x * 64 + lane;   // [0, KVH)

    float sre = 0.f, sim = 0.f;
    for (int c = w; c < nQuads; c += 8) {
        float2 p = __half22float2(partials[(size_t)c * KVH + kvs]);
        sre += p.x;
        sim += p.y;
    }
    __shared__ float2 red[8][64];
    red[w][lane] = make_float2(sre, sim);
    __syncthreads();

    if (w == 0) {
        sre = 0.f; sim = 0.f;
#pragma unroll
        for (int j = 0; j < 8; ++j) {
            float2 p = red[j][lane];
            sre += p.x; sim += p.y;
        }
        const int k3 = kvs / NPHPAD;
        const int s  = kvs - k3 * NPHPAD;
        float cont = 0.f;
        float inv[9], det;
        inv3(cell, inv, &det);
        if (s < NPH) {
            int n1i, k2;
            decode_pair(s, &n1i, &k2);
            float n1 = (float)n1i;
            float n2 = (float)(k2 - NKHALF);
            float n3 = (float)(k3 - NKHALF);
            float factor = (s == 544) ? ((n3 != 0.f) ? 1.f : 0.f) : 2.f;

            const float twopi = 6.28318530717958647692f;
            float kx = twopi * (n1*inv[0] + n2*inv[1] + n3*inv[2]);
            float ky = twopi * (n1*inv[3] + n2*inv[4] + n3*inv[5]);
            float kz = twopi * (n1*inv[6] + n2*inv[7] + n3*inv[8]);
            float ksq = kx*kx + ky*ky + kz*kz;
            float kfac = 0.f;
            for (int j = 0; j < nshift; ++j) {
                float mt = -expf(2.0f * shift1[j]);
                kfac += amp1[j] * expf(ksq * mt);
            }
            cont = factor * kfac * (sre*sre + sim*sim) / det;
        }
        for (int off = 32; off; off >>= 1) cont += __shfl_down(cont, off, 64);
        if (lane == 0) {
            float add = cont;
            if (blockIdx.x == 0) add += ene[0];
            atomicAdd(out, add);
        }
    }
}

extern "C" void kernel_launch(void* const* d_in, const int* in_sizes, int n_in,
                              void* d_out, int out_size, void* d_ws, size_t ws_size,
                              hipStream_t stream) {
    const float* pos    = (const float*)d_in[0];
    const float* q      = (const float*)d_in[1];
    const float* cell   = (const float*)d_in[2];
    const float* shift1 = (const float*)d_in[3];
    const float* amp1   = (const float*)d_in[4];
    const float* ene    = (const float*)d_in[5];
    // d_in[6] = batch (unused: single system)

    const int n      = in_sizes[0] / 3;
    const int nshift = in_sizes[3];

    __half2* partials = (__half2*)d_ws;

    const int atomsPerBlock = CHUNK * WAVES_A;               // 64
    const int nOcts = (n + atomsPerBlock - 1) / atomsPerBlock;  // 32 for n=2000

    sf_fused<<<9 * nOcts, 512, 0, stream>>>(pos, q, cell, partials,
                                            (float*)d_out, n);
    reduce_weight<<<RW_BLOCKS, 512, 0, stream>>>(partials, nOcts, cell,
                                                 shift1, amp1, nshift,
                                                 ene, (float*)d_out);
}

// Round 8
// 22.735 us; speedup vs baseline: 2.9853x; 1.1978x over previous
//
#include <hip/hip_runtime.h>
#include <hip/hip_fp16.h>
#include <math.h>

#define NKHALF 16
#define NG 33                 // 2*NKHALF+1
#define NPH 545               // hemisphere (k1,k2) pairs
#define NPHPAD 576            // padded to 9 groups of 64
#define KVH (NG * NPHPAD)     // 19008 padded hemisphere k-slots
#define RW_BLOCKS (KVH / 64)  // 297, exact
#define CHUNK 9               // atoms per wave
#define WAVES_A 8             // waves per A block (same pair-group)
// atoms/block = 72 -> nOcts = ceil(2000/72) = 28 -> grid A = 9*28 = 252 <= 256 CUs

__device__ __forceinline__ void inv3(const float* __restrict__ m, float* inv, float* detOut) {
    float c00 = m[4]*m[8] - m[5]*m[7];
    float c01 = m[5]*m[6] - m[3]*m[8];
    float c02 = m[3]*m[7] - m[4]*m[6];
    float det = m[0]*c00 + m[1]*c01 + m[2]*c02;
    float id  = 1.0f / det;
    inv[0] = c00 * id;
    inv[1] = (m[2]*m[7] - m[1]*m[8]) * id;
    inv[2] = (m[1]*m[5] - m[2]*m[4]) * id;
    inv[3] = c01 * id;
    inv[4] = (m[0]*m[8] - m[2]*m[6]) * id;
    inv[5] = (m[2]*m[3] - m[0]*m[5]) * id;
    inv[6] = c02 * id;
    inv[7] = (m[1]*m[6] - m[0]*m[7]) * id;
    inv[8] = (m[0]*m[4] - m[1]*m[3]) * id;
    *detOut = det;
}

// hp -> (n1, k2):
//   hp in [0,528):   n1 = hp/33 + 1, k2 = hp%33
//   hp in [528,544): n1 = 0,         k2 = hp-528+17
//   hp == 544:       n1 = 0,         k2 = 16
__device__ __forceinline__ void decode_pair(int hp, int* n1, int* k2) {
    if (hp < 528)      { int a = hp / 33; *n1 = a + 1; *k2 = hp - a * 33; }
    else if (hp < 544) { *n1 = 0; *k2 = hp - 528 + 17; }
    else               { *n1 = 0; *k2 = 16; }
}

// Kernel A: block = 512 thr = 8 waves, all on pair-group pg; wave w handles
// atom chunk oct*8+w (9 atoms). Lanes 0..8 precompute per-atom uniform values
// (one sincos each); broadcast via shfl; each lane does ONE sincos (its pair
// phase at n3=-16) then walks 33 k3 by in-register complex rotation.
// 8 waves LDS-combine -> one fp16 partial per block. Grid = 252 blocks
// (one per CU, no quantization stragglers).
__global__ __launch_bounds__(512) void sf_fused(
        const float* __restrict__ pos,
        const float* __restrict__ q,
        const float* __restrict__ cell,
        __half2* __restrict__ partials,
        float* __restrict__ out0,
        int n) {
    if (blockIdx.x == 0 && threadIdx.x == 0) out0[0] = 0.f;

    const int pg   = blockIdx.x % 9;
    const int oct  = blockIdx.x / 9;
    const int w    = threadIdx.x >> 6;
    const int lane = threadIdx.x & 63;
    const int slot = pg * 64 + lane;          // 0..575
    int hp = slot > 544 ? 544 : slot;
    int n1i, k2;
    decode_pair(hp, &n1i, &k2);
    const float n1f = (float)n1i;
    const float n2f = (float)(k2 - NKHALF);

    float inv[9], det;
    inv3(cell, inv, &det);
    const float twopi = 6.28318530717958647692f;

    float2 S[NG];
#pragma unroll
    for (int i = 0; i < NG; ++i) S[i] = make_float2(0.f, 0.f);

    const int a0 = (oct * WAVES_A + w) * CHUNK;
    int na = n - a0;
    if (na > CHUNK) na = CHUNK;

    // lanes 0..na-1 precompute per-atom wave-uniform values
    float v0l = 0.f, v1l = 0.f, v2l = 0.f, qal = 0.f, c3l = 1.f, s3l = 0.f;
    if (lane < na) {
        int a = a0 + lane;
        float px = pos[3*a + 0], py = pos[3*a + 1], pz = pos[3*a + 2];
        qal = q[a];
        v0l = twopi * (inv[0]*px + inv[3]*py + inv[6]*pz);
        v1l = twopi * (inv[1]*px + inv[4]*py + inv[7]*pz);
        v2l = twopi * (inv[2]*px + inv[5]*py + inv[8]*pz);
        __sincosf(v2l, &s3l, &c3l);
    }

    for (int i = 0; i < na; ++i) {
        float v0 = __shfl(v0l, i, 64);
        float v1 = __shfl(v1l, i, 64);
        float v2 = __shfl(v2l, i, 64);
        float qa = __shfl(qal, i, 64);
        float c3 = __shfl(c3l, i, 64);
        float s3 = __shfl(s3l, i, 64);

        // phase at k3 index 0 (n3 = -16)
        float ph = fmaf(n1f, v0, fmaf(n2f, v1, -16.f * v2));
        float s, cc;
        __sincosf(ph, &s, &cc);
        float2 cur = make_float2(qa * cc, qa * s);

#pragma unroll
        for (int k3 = 0; k3 < NG; ++k3) {
            S[k3].x += cur.x;
            S[k3].y += cur.y;
            if (k3 < NG - 1) {
                float2 t;
                t.x = fmaf(-cur.y, s3, cur.x * c3);
                t.y = fmaf( cur.x, s3, cur.y * c3);
                cur = t;
            }
        }
    }

    // cross-wave combine through LDS (fp16), one partial per block
    __shared__ __half2 ls[WAVES_A][NG][64];
#pragma unroll
    for (int k3 = 0; k3 < NG; ++k3) {
        ls[w][k3][lane] = __floats2half2_rn(S[k3].x, S[k3].y);
    }
    __syncthreads();

    __half2* __restrict__ out = partials + (size_t)oct * KVH;
    for (int idx = threadIdx.x; idx < NG * 64; idx += 512) {
        const int k3 = idx >> 6;
        const int l  = idx & 63;
        float sx = 0.f, sy = 0.f;
#pragma unroll
        for (int j = 0; j < WAVES_A; ++j) {
            float2 p = __half22float2(ls[j][k3][l]);
            sx += p.x; sy += p.y;
        }
        out[(size_t)k3 * NPHPAD + pg * 64 + l] = __floats2half2_rn(sx, sy);
    }
}

// Kernel B: block = 512 thr (8 waves) per 64 k-slots; waves split the oct
// dim, LDS combine, wave 0 weights (incl. 1/volume) and one atomicAdd per
// block; block 0 adds ene_factor.
__global__ __launch_bounds__(512) void reduce_weight(
        const __half2* __restrict__ partials, int nOcts,
        const float* __restrict__ cell,
        const float* __restrict__ shift1, const float* __restrict__ amp1,
        int nshift,
        const float* __restrict__ ene,
        float* __restrict__ out) {
    const int lane = threadIdx.x & 63;
    const int w    = threadIdx.x >> 6;         // 0..7
    const int kvs  = blockIdx.x * 64 + lane;   // [0, KVH)

    float sre = 0.f, sim = 0.f;
    for (int c = w; c < nOcts; c += 8) {
        float2 p = __half22float2(partials[(size_t)c * KVH + kvs]);
        sre += p.x;
        sim += p.y;
    }
    __shared__ float2 red[8][64];
    red[w][lane] = make_float2(sre, sim);
    __syncthreads();

    if (w == 0) {
        sre = 0.f; sim = 0.f;
#pragma unroll
        for (int j = 0; j < 8; ++j) {
            float2 p = red[j][lane];
            sre += p.x; sim += p.y;
        }
        const int k3 = kvs / NPHPAD;
        const int s  = kvs - k3 * NPHPAD;
        float cont = 0.f;
        float inv[9], det;
        inv3(cell, inv, &det);
        if (s < NPH) {
            int n1i, k2;
            decode_pair(s, &n1i, &k2);
            float n1 = (float)n1i;
            float n2 = (float)(k2 - NKHALF);
            float n3 = (float)(k3 - NKHALF);
            float factor = (s == 544) ? ((n3 != 0.f) ? 1.f : 0.f) : 2.f;

            const float twopi = 6.28318530717958647692f;
            float kx = twopi * (n1*inv[0] + n2*inv[1] + n3*inv[2]);
            float ky = twopi * (n1*inv[3] + n2*inv[4] + n3*inv[5]);
            float kz = twopi * (n1*inv[6] + n2*inv[7] + n3*inv[8]);
            float ksq = kx*kx + ky*ky + kz*kz;
            float kfac = 0.f;
            for (int j = 0; j < nshift; ++j) {
                float mt = -expf(2.0f * shift1[j]);
                kfac += amp1[j] * expf(ksq * mt);
            }
            cont = factor * kfac * (sre*sre + sim*sim) / det;
        }
        for (int off = 32; off; off >>= 1) cont += __shfl_down(cont, off, 64);
        if (lane == 0) {
            float add = cont;
            if (blockIdx.x == 0) add += ene[0];
            atomicAdd(out, add);
        }
    }
}

extern "C" void kernel_launch(void* const* d_in, const int* in_sizes, int n_in,
                              void* d_out, int out_size, void* d_ws, size_t ws_size,
                              hipStream_t stream) {
    const float* pos    = (const float*)d_in[0];
    const float* q      = (const float*)d_in[1];
    const float* cell   = (const float*)d_in[2];
    const float* shift1 = (const float*)d_in[3];
    const float* amp1   = (const float*)d_in[4];
    const float* ene    = (const float*)d_in[5];
    // d_in[6] = batch (unused: single system)

    const int n      = in_sizes[0] / 3;
    const int nshift = in_sizes[3];

    __half2* partials = (__half2*)d_ws;

    const int atomsPerBlock = CHUNK * WAVES_A;                  // 72
    const int nOcts = (n + atomsPerBlock - 1) / atomsPerBlock;  // 28 for n=2000

    sf_fused<<<9 * nOcts, 512, 0, stream>>>(pos, q, cell, partials,
                                            (float*)d_out, n);
    reduce_weight<<<RW_BLOCKS, 512, 0, stream>>>(partials, nOcts, cell,
                                                 shift1, amp1, nshift,
                                                 ene, (float*)d_out);
}

// Round 9
// 21.154 us; speedup vs baseline: 3.2085x; 1.0748x over previous
//
#include <hip/hip_runtime.h>
#include <hip/hip_fp16.h>
#include <math.h>

#define NKHALF 16
#define NG 33                 // 2*NKHALF+1
#define NPH 545               // hemisphere (k1,k2) pairs
#define NPHPAD 576            // padded to 9 groups of 64
#define KVH (NG * NPHPAD)     // 19008 padded hemisphere k-slots
#define RW_BLOCKS (KVH / 64)  // 297, exact
#define CHUNK 9               // atoms per wave
#define WAVES_A 8             // waves per A block (same pair-group)
// atoms/block = 72 -> nOcts = ceil(2000/72) = 28 -> grid A = 9*28 = 252 <= 256 CUs

typedef float f2 __attribute__((ext_vector_type(2)));   // packs to v_pk_*_f32

__device__ __forceinline__ void inv3(const float* __restrict__ m, float* inv, float* detOut) {
    float c00 = m[4]*m[8] - m[5]*m[7];
    float c01 = m[5]*m[6] - m[3]*m[8];
    float c02 = m[3]*m[7] - m[4]*m[6];
    float det = m[0]*c00 + m[1]*c01 + m[2]*c02;
    float id  = 1.0f / det;
    inv[0] = c00 * id;
    inv[1] = (m[2]*m[7] - m[1]*m[8]) * id;
    inv[2] = (m[1]*m[5] - m[2]*m[4]) * id;
    inv[3] = c01 * id;
    inv[4] = (m[0]*m[8] - m[2]*m[6]) * id;
    inv[5] = (m[2]*m[3] - m[0]*m[5]) * id;
    inv[6] = c02 * id;
    inv[7] = (m[1]*m[6] - m[0]*m[7]) * id;
    inv[8] = (m[0]*m[4] - m[1]*m[3]) * id;
    *detOut = det;
}

// hp -> (n1, k2):
//   hp in [0,528):   n1 = hp/33 + 1, k2 = hp%33
//   hp in [528,544): n1 = 0,         k2 = hp-528+17
//   hp == 544:       n1 = 0,         k2 = 16
__device__ __forceinline__ void decode_pair(int hp, int* n1, int* k2) {
    if (hp < 528)      { int a = hp / 33; *n1 = a + 1; *k2 = hp - a * 33; }
    else if (hp < 544) { *n1 = 0; *k2 = hp - 528 + 17; }
    else               { *n1 = 0; *k2 = 16; }
}

// Kernel A: block = 512 thr = 8 waves, all on pair-group pg; wave w handles
// atom chunk oct*8+w (9 atoms). Lanes 0..8 precompute per-atom uniform values
// (one sincos each); broadcast via shfl; each lane does ONE sincos (its pair
// phase at n3=-16) then walks 33 k3 by PACKED complex rotation
// (v_pk_add_f32 / v_pk_fma_f32: 3 packed ops per k3 instead of 6 scalar).
// 8 waves LDS-combine -> one fp16 partial per block. Grid = 252 blocks.
__global__ __launch_bounds__(512) void sf_fused(
        const float* __restrict__ pos,
        const float* __restrict__ q,
        const float* __restrict__ cell,
        __half2* __restrict__ partials,
        float* __restrict__ out0,
        int n) {
    if (blockIdx.x == 0 && threadIdx.x == 0) out0[0] = 0.f;

    const int pg   = blockIdx.x % 9;
    const int oct  = blockIdx.x / 9;
    const int w    = threadIdx.x >> 6;
    const int lane = threadIdx.x & 63;
    const int slot = pg * 64 + lane;          // 0..575
    int hp = slot > 544 ? 544 : slot;
    int n1i, k2;
    decode_pair(hp, &n1i, &k2);
    const float n1f = (float)n1i;
    const float n2f = (float)(k2 - NKHALF);

    float inv[9], det;
    inv3(cell, inv, &det);
    const float twopi = 6.28318530717958647692f;

    f2 S[NG];
#pragma unroll
    for (int i = 0; i < NG; ++i) S[i] = (f2){0.f, 0.f};

    const int a0 = (oct * WAVES_A + w) * CHUNK;
    int na = n - a0;
    if (na > CHUNK) na = CHUNK;

    // lanes 0..na-1 precompute per-atom wave-uniform values
    float v0l = 0.f, v1l = 0.f, v2l = 0.f, qal = 0.f, c3l = 1.f, s3l = 0.f;
    if (lane < na) {
        int a = a0 + lane;
        float px = pos[3*a + 0], py = pos[3*a + 1], pz = pos[3*a + 2];
        qal = q[a];
        v0l = twopi * (inv[0]*px + inv[3]*py + inv[6]*pz);
        v1l = twopi * (inv[1]*px + inv[4]*py + inv[7]*pz);
        v2l = twopi * (inv[2]*px + inv[5]*py + inv[8]*pz);
        __sincosf(v2l, &s3l, &c3l);
    }

    for (int i = 0; i < na; ++i) {
        float v0 = __shfl(v0l, i, 64);
        float v1 = __shfl(v1l, i, 64);
        float v2 = __shfl(v2l, i, 64);
        float qa = __shfl(qal, i, 64);
        float c3 = __shfl(c3l, i, 64);
        float s3 = __shfl(s3l, i, 64);

        // phase at k3 index 0 (n3 = -16)
        float ph = fmaf(n1f, v0, fmaf(n2f, v1, -16.f * v2));
        float s, cc;
        __sincosf(ph, &s, &cc);
        f2 cur = (f2){qa * cc, qa * s};

        const f2 e3a = (f2){c3, s3};     // rotation: cur' = (x,x)*e3a + (y,y)*e3b
        const f2 e3b = (f2){-s3, c3};

#pragma unroll
        for (int k3 = 0; k3 < NG; ++k3) {
            S[k3] += cur;                               // v_pk_add_f32
            if (k3 < NG - 1) {
                f2 xx = (f2){cur.x, cur.x};             // op_sel-foldable splats
                f2 yy = (f2){cur.y, cur.y};
                cur = xx * e3a + yy * e3b;              // v_pk_mul + v_pk_fma
            }
        }
    }

    // cross-wave combine through LDS (fp16), one partial per block
    __shared__ __half2 ls[WAVES_A][NG][64];
#pragma unroll
    for (int k3 = 0; k3 < NG; ++k3) {
        ls[w][k3][lane] = __floats2half2_rn(S[k3].x, S[k3].y);
    }
    __syncthreads();

    __half2* __restrict__ out = partials + (size_t)oct * KVH;
    for (int idx = threadIdx.x; idx < NG * 64; idx += 512) {
        const int k3 = idx >> 6;
        const int l  = idx & 63;
        float sx = 0.f, sy = 0.f;
#pragma unroll
        for (int j = 0; j < WAVES_A; ++j) {
            float2 p = __half22float2(ls[j][k3][l]);
            sx += p.x; sy += p.y;
        }
        out[(size_t)k3 * NPHPAD + pg * 64 + l] = __floats2half2_rn(sx, sy);
    }
}

// Kernel B: block = 512 thr (8 waves) per 64 k-slots; waves split the oct
// dim, LDS combine, wave 0 weights (incl. 1/volume) and one atomicAdd per
// block; block 0 adds ene_factor.
__global__ __launch_bounds__(512) void reduce_weight(
        const __half2* __restrict__ partials, int nOcts,
        const float* __restrict__ cell,
        const float* __restrict__ shift1, const float* __restrict__ amp1,
        int nshift,
        const float* __restrict__ ene,
        float* __restrict__ out) {
    const int lane = threadIdx.x & 63;
    const int w    = threadIdx.x >> 6;         // 0..7
    const int kvs  = blockIdx.x * 64 + lane;   // [0, KVH)

    float sre = 0.f, sim = 0.f;
    for (int c = w; c < nOcts; c += 8) {
        float2 p = __half22float2(partials[(size_t)c * KVH + kvs]);
        sre += p.x;
        sim += p.y;
    }
    __shared__ float2 red[8][64];
    red[w][lane] = make_float2(sre, sim);
    __syncthreads();

    if (w == 0) {
        sre = 0.f; sim = 0.f;
#pragma unroll
        for (int j = 0; j < 8; ++j) {
            float2 p = red[j][lane];
            sre += p.x; sim += p.y;
        }
        const int k3 = kvs / NPHPAD;
        const int s  = kvs - k3 * NPHPAD;
        float cont = 0.f;
        float inv[9], det;
        inv3(cell, inv, &det);
        if (s < NPH) {
            int n1i, k2;
            decode_pair(s, &n1i, &k2);
            float n1 = (float)n1i;
            float n2 = (float)(k2 - NKHALF);
            float n3 = (float)(k3 - NKHALF);
            float factor = (s == 544) ? ((n3 != 0.f) ? 1.f : 0.f) : 2.f;

            const float twopi = 6.28318530717958647692f;
            float kx = twopi * (n1*inv[0] + n2*inv[1] + n3*inv[2]);
            float ky = twopi * (n1*inv[3] + n2*inv[4] + n3*inv[5]);
            float kz = twopi * (n1*inv[6] + n2*inv[7] + n3*inv[8]);
            float ksq = kx*kx + ky*ky + kz*kz;
            float kfac = 0.f;
            for (int j = 0; j < nshift; ++j) {
                float mt = -expf(2.0f * shift1[j]);
                kfac += amp1[j] * expf(ksq * mt);
            }
            cont = factor * kfac * (sre*sre + sim*sim) / det;
        }
        for (int off = 32; off; off >>= 1) cont += __shfl_down(cont, off, 64);
        if (lane == 0) {
            float add = cont;
            if (blockIdx.x == 0) add += ene[0];
            atomicAdd(out, add);
        }
    }
}

extern "C" void kernel_launch(void* const* d_in, const int* in_sizes, int n_in,
                              void* d_out, int out_size, void* d_ws, size_t ws_size,
                              hipStream_t stream) {
    const float* pos    = (const float*)d_in[0];
    const float* q      = (const float*)d_in[1];
    const float* cell   = (const float*)d_in[2];
    const float* shift1 = (const float*)d_in[3];
    const float* amp1   = (const float*)d_in[4];
    const float* ene    = (const float*)d_in[5];
    // d_in[6] = batch (unused: single system)

    const int n      = in_sizes[0] / 3;
    const int nshift = in_sizes[3];

    __half2* partials = (__half2*)d_ws;

    const int atomsPerBlock = CHUNK * WAVES_A;                  // 72
    const int nOcts = (n + atomsPerBlock - 1) / atomsPerBlock;  // 28 for n=2000

    sf_fused<<<9 * nOcts, 512, 0, stream>>>(pos, q, cell, partials,
                                            (float*)d_out, n);
    reduce_weight<<<RW_BLOCKS, 512, 0, stream>>>(partials, nOcts, cell,
                                                 shift1, amp1, nshift,
                                                 ene, (float*)d_out);
}